// Round 10
// baseline (281.727 us; speedup 1.0000x reference)
//
#include <hip/hip_runtime.h>

// ROIAlign3d: x=[2,256,16,64,64] f32, rois=[64,5] -> out=[64,256,16,7,7] f32.
// R11: persistent pipelined blocks. Grid = 1792 (7 blocks/CU by LDS), each
// block grid-strides over ~18 units (unit = (c, roi, T-half), P=8 planes,
// exact-box float4 staging as R7). Double-buffered LDS box; per iteration:
//   ds_write unit k (regs->LDS, vmcnt-waits loads issued last iter)
//   compute geo + issue global loads for unit k+1 (into regs)
//   __syncthreads()                      // one barrier per unit
//   compute unit k from LDS (k+1 loads in flight underneath)
// The staging-load latency + vmcnt drain is thereby covered by the previous
// unit's compute instead of stalling a fresh tiny block. No LDS tables:
// y/x prep per-lane in registers (VALU has headroom). Phase B = R7 grouped
// (lane=plane, bin uniform per 8-lane group) + R10 pair-adjacent x-taps.

#define GRID  1792
#define NU    32768
#define NBINS 49
#define MAXB4 85            // worst-case float4 per plane box (17 rows x 5)
#define SEG4  (8 * MAXB4)   // 680 float4 per buffer

struct Geo {
    int   pbase, obase;     // input elem base (c,t0); output dword base
    float sw, sh, bw, bh;
    int   y_lo, x4_lo, rowst, ncol4, nrc4, PS4;
    unsigned inv_c;
};

__device__ __forceinline__ Geo make_geo(int u, const float* __restrict__ rois)
{
    constexpr int C = 256, T = 16, H = 64, W = 64;
    constexpr float SCALE = 0.0625f;
    Geo G;
    const int c  = u >> 7;
    const int rg = u & 127;
    const int r  = rg >> 1;
    const int g  = rg & 1;

    const float r1 = rois[r * 5 + 1], r2 = rois[r * 5 + 2];
    const float r3 = rois[r * 5 + 3], r4 = rois[r * 5 + 4];
    const int   bidx = (int)rois[r * 5 + 0];

    G.sw = r1 * SCALE; G.sh = r2 * SCALE;
    G.bw = fmaxf(r3 * SCALE - G.sw, 1.0f) * (1.0f / 7.0f);
    G.bh = fmaxf(r4 * SCALE - G.sh, 1.0f) * (1.0f / 7.0f);

    const float ys_min = G.sh + 0.25f * G.bh, ys_max = G.sh + 6.75f * G.bh;
    const float xs_min = G.sw + 0.25f * G.bw, xs_max = G.sw + 6.75f * G.bw;
    G.y_lo = (int)floorf(fminf(fmaxf(ys_min, 0.0f), (float)(H - 1)));
    const int y0mx = (int)floorf(fminf(fmaxf(ys_max, 0.0f), (float)(H - 1)));
    const int x_lo = (int)floorf(fminf(fmaxf(xs_min, 0.0f), (float)(W - 1)));
    const int x0mx = (int)floorf(fminf(fmaxf(xs_max, 0.0f), (float)(W - 1)));
    G.x4_lo = x_lo & ~3;

    const int nrows = min(y0mx + 1, H - 1) - G.y_lo + 1;   // <= 17
    G.ncol4 = ((x0mx + 1 - G.x4_lo) >> 2) + 1;             // <= 5
    G.rowst = G.ncol4 << 2;
    G.nrc4  = nrows * G.ncol4;                             // <= 85
    G.PS4   = G.nrc4 | 1;                                  // odd plane stride
    G.inv_c = 65535u / (unsigned)G.ncol4 + 1u;             // exact for rem<96

    G.pbase = ((bidx * C + c) * T + (g << 3)) << 12;
    G.obase = (((r * C + c) * T) + (g << 3)) * NBINS;
    return G;
}

__global__ __launch_bounds__(256, 7) void roialign3d_kernel(
    const float* __restrict__ x, const float* __restrict__ rois,
    float* __restrict__ out)
{
    constexpr int TOT = 2 * 256 * 16 * 64 * 64;

    __shared__ float4 s_box[2][SEG4];        // 21,760 B total

    const int tid  = threadIdx.x;
    const int pl_s = tid >> 5;               // staging plane 0..7
    const int l32  = tid & 31;

    // Phase-B thread mapping (R7 grouped)
    const int l    = tid & 63;
    const int w    = tid >> 6;
    const int plb  = l & 7;                  // plane within unit
    const int slot = (w << 3) + (l >> 3);    // 0..31

    int u = (int)blockIdx.x;
    Geo G = make_geo(u, rois);

    float4 tmp0, tmp1, tmp2;
    int    d0 = -1, d1 = -1, d2 = -1;

    // issue loads for first unit
    {
#pragma unroll
        for (int it = 0; it < 3; ++it) {
            const int i2 = l32 + (it << 5);
            if (i2 < G.nrc4) {
                const int row = (int)(((unsigned)i2 * G.inv_c) >> 16);
                const int col = i2 - row * G.ncol4;
                int sidx = G.pbase + (pl_s << 12) + ((G.y_lo + row) << 6)
                         + G.x4_lo + (col << 2);
                sidx = min(sidx, TOT - 4);
                const float4 v = *(const float4*)(x + sidx);
                const int dd = pl_s * G.PS4 + i2;
                if (it == 0) { tmp0 = v; d0 = dd; }
                if (it == 1) { tmp1 = v; d1 = dd; }
                if (it == 2) { tmp2 = v; d2 = dd; }
            } else {
                if (it == 0) d0 = -1;
                if (it == 1) d1 = -1;
                if (it == 2) d2 = -1;
            }
        }
    }

    int pbuf = 0;
    for (;;) {
        // ---- ds_write unit u's box (waits its loads) ----
        if (d0 >= 0) s_box[pbuf][d0] = tmp0;
        if (d1 >= 0) s_box[pbuf][d1] = tmp1;
        if (d2 >= 0) s_box[pbuf][d2] = tmp2;

        // ---- geo + loads for next unit (fly under compute below) ----
        const int u_nxt = u + GRID;
        const bool has_nxt = (u_nxt < NU);
        Geo Gn;
        if (has_nxt) {
            Gn = make_geo(u_nxt, rois);
#pragma unroll
            for (int it = 0; it < 3; ++it) {
                const int i2 = l32 + (it << 5);
                if (i2 < Gn.nrc4) {
                    const int row = (int)(((unsigned)i2 * Gn.inv_c) >> 16);
                    const int col = i2 - row * Gn.ncol4;
                    int sidx = Gn.pbase + (pl_s << 12) + ((Gn.y_lo + row) << 6)
                             + Gn.x4_lo + (col << 2);
                    sidx = min(sidx, TOT - 4);
                    const float4 v = *(const float4*)(x + sidx);
                    const int dd = pl_s * Gn.PS4 + i2;
                    if (it == 0) { tmp0 = v; d0 = dd; }
                    if (it == 1) { tmp1 = v; d1 = dd; }
                    if (it == 2) { tmp2 = v; d2 = dd; }
                } else {
                    if (it == 0) d0 = -1;
                    if (it == 1) d1 = -1;
                    if (it == 2) d2 = -1;
                }
            }
        }

        __syncthreads();

        // ---- compute unit u from s_box[pbuf] ----
        {
            const float* __restrict__ bx =
                (const float*)&s_box[pbuf][0] + plb * (G.PS4 << 2);
            float* __restrict__ op = out + (size_t)(G.obase + plb * NBINS);

#pragma unroll
            for (int h = 0; h < 2; ++h) {
                const int bin = slot + (h << 5);
                if (bin < NBINS) {
                    const int ph = (bin * 9363) >> 16;   // bin/7
                    const int pw = bin - ph * 7;

                    // y-prep (registers)
                    int roA, roB, roC, roD;
                    float wyA, wyB, wyC, wyD;
                    {
                        const float ys0 = G.sh + ((float)ph + 0.25f) * G.bh;
                        const float ys1 = G.sh + ((float)ph + 0.75f) * G.bh;
                        const float m0 = (ys0 >= -1.0f && ys0 <= 64.0f) ? 0.5f : 0.0f;
                        const float m1 = (ys1 >= -1.0f && ys1 <= 64.0f) ? 0.5f : 0.0f;
                        const float yc0 = fminf(fmaxf(ys0, 0.0f), 63.0f);
                        const float yc1 = fminf(fmaxf(ys1, 0.0f), 63.0f);
                        const int y00 = (int)yc0, y10 = (int)yc1;
                        const int y01 = min(y00 + 1, 63), y11 = min(y10 + 1, 63);
                        const float ly0 = yc0 - (float)y00, ly1 = yc1 - (float)y10;
                        roA = (y00 - G.y_lo) * G.rowst; wyA = (1.0f - ly0) * m0;
                        roB = (y01 - G.y_lo) * G.rowst; wyB = ly0 * m0;
                        roC = (y10 - G.y_lo) * G.rowst; wyC = (1.0f - ly1) * m1;
                        roD = (y11 - G.y_lo) * G.rowst; wyD = ly1 * m1;
                    }
                    // x-prep (registers, pair-adjacent)
                    int cx0, cx1;
                    float wxA, wxB, wxC, wxD;
                    {
                        const float xs0 = G.sw + ((float)pw + 0.25f) * G.bw;
                        const float xs1 = G.sw + ((float)pw + 0.75f) * G.bw;
                        const float m0 = (xs0 >= -1.0f && xs0 <= 64.0f) ? 0.5f : 0.0f;
                        const float m1 = (xs1 >= -1.0f && xs1 <= 64.0f) ? 0.5f : 0.0f;
                        const float xc0 = fminf(fmaxf(xs0, 0.0f), 63.0f);
                        const float xc1 = fminf(fmaxf(xs1, 0.0f), 63.0f);
                        int x00 = (int)xc0, x10 = (int)xc1;
                        float lx0 = xc0 - (float)x00, lx1 = xc1 - (float)x10;
                        if (x00 > 62) { x00 = 62; lx0 = 1.0f; }
                        if (x10 > 62) { x10 = 62; lx1 = 1.0f; }
                        cx0 = x00 - G.x4_lo; cx1 = x10 - G.x4_lo;
                        wxA = (1.0f - lx0) * m0; wxB = lx0 * m0;
                        wxC = (1.0f - lx1) * m1; wxD = lx1 * m1;
                    }

                    const float* qA = bx + roA;
                    const float* qB = bx + roB;
                    const float* qC = bx + roC;
                    const float* qD = bx + roD;
                    float acc;
                    acc  = wyA * (wxA * qA[cx0] + wxB * qA[cx0 + 1]
                                + wxC * qA[cx1] + wxD * qA[cx1 + 1]);
                    acc += wyB * (wxA * qB[cx0] + wxB * qB[cx0 + 1]
                                + wxC * qB[cx1] + wxD * qB[cx1 + 1]);
                    acc += wyC * (wxA * qC[cx0] + wxB * qC[cx0 + 1]
                                + wxC * qC[cx1] + wxD * qC[cx1 + 1]);
                    acc += wyD * (wxA * qD[cx0] + wxB * qD[cx0 + 1]
                                + wxC * qD[cx1] + wxD * qD[cx1 + 1]);
                    op[bin] = acc;
                }
            }
        }

        if (u + GRID >= NU) break;
        u = u + GRID;
        G = Gn;
        pbuf ^= 1;
    }
}

extern "C" void kernel_launch(void* const* d_in, const int* in_sizes, int n_in,
                              void* d_out, int out_size, void* d_ws, size_t ws_size,
                              hipStream_t stream) {
    const float* x    = (const float*)d_in[0];
    const float* rois = (const float*)d_in[1];
    float* out = (float*)d_out;

    // persistent-ish: 1792 blocks (7/CU), each pipelines ~18 units
    roialign3d_kernel<<<dim3(GRID), dim3(256), 0, stream>>>(x, rois, out);
}